// Round 1
// baseline (1064.847 us; speedup 1.0000x reference)
//
#include <hip/hip_runtime.h>
#include <hip/hip_fp16.h>

#define S_DIM 2048
#define D_K   64
#define BQ    64      // q rows per workgroup (16 per wave x 4 waves)
#define BK    64      // key block per iteration
#define KSTR  72      // LDS row stride in halves: 64+8 pad keeps 16B align, spreads banks
#define NEGV  -1e9f

typedef _Float16 f16;
typedef f16  f16x2 __attribute__((ext_vector_type(2)));
typedef f16  f16x4 __attribute__((ext_vector_type(4)));
typedef f16  f16x8 __attribute__((ext_vector_type(8)));
typedef float f32x4 __attribute__((ext_vector_type(4)));

// ---------------------------------------------------------------------------
// Probe: classify attn_mask storage. flag bit1 -> float32, bit0 -> byte,
// neither -> int32 {0,1}. Byte-packed random bits give words >1 with
// overwhelming probability in 4096 words; float gives exact 0x3f800000.
// ---------------------------------------------------------------------------
__global__ void mask_probe(const unsigned int* __restrict__ mw, int* __restrict__ flag) {
    int t = threadIdx.x;
    unsigned int isFloat = 0u, gt1 = 0u;
#pragma unroll
    for (int i = 0; i < 16; ++i) {
        unsigned int v = mw[t * 16 + i];
        isFloat |= (v == 0x3f800000u) ? 1u : 0u;
        gt1     |= (v > 1u) ? 1u : 0u;
    }
    if (isFloat) atomicOr(flag, 2);
    else if (gt1) atomicOr(flag, 1);
}

// ---------------------------------------------------------------------------
// Flash-style masked attention with matrix elementwise scaling.
// Layouts (gfx950 mfma_f32_16x16x32_f16, m89/m120-verified):
//   A-frag: A[m = lane&15][k = (lane>>4)*8 + j]
//   B-frag: B[k = (lane>>4)*8 + j][n = lane&15]
//   C/D   : row = (lane>>4)*4 + reg, col = lane&15
// ---------------------------------------------------------------------------
__global__ __launch_bounds__(256, 4)
void attn_kernel(const float* __restrict__ Qg, const float* __restrict__ Kg,
                 const float* __restrict__ Vg, const void* __restrict__ maskp,
                 const float* __restrict__ Mg, float* __restrict__ Og,
                 const int* __restrict__ flagp)
{
    const int bh  = blockIdx.y;          // 0..31  (b*16+h)
    const int q0  = blockIdx.x * BQ;     // q tile origin
    const int tid = threadIdx.x;
    const int wv  = tid >> 6;            // wave 0..3
    const int ln  = tid & 63;
    const int n16 = ln & 15;
    const int qd  = ln >> 4;             // quad 0..3

    const int fl   = *flagp;
    const int mfmt = (fl & 2) ? 2 : (fl & 1);   // 0=int32 1=byte 2=float32

    const size_t bhQ = (size_t)bh * S_DIM * D_K;
    const float* Qp = Qg + bhQ;
    const float* Kp = Kg + bhQ;
    const float* Vp = Vg + bhQ;
    const size_t bhS = (size_t)bh * S_DIM * S_DIM;
    const float*         Mp = Mg + bhS;
    const unsigned char* mB = (const unsigned char*)maskp + bhS;
    const int*           mI = (const int*)maskp + bhS;
    const float*         mF = (const float*)maskp + bhS;

    __shared__ f16 Ksh[BK][KSTR];      // K block, row-major [key][dk]
    __shared__ f16 Vsh[D_K][KSTR];     // V block, transposed [dk][key]
    __shared__ f16 Psh[4][16][KSTR];   // per-wave P tile [qrow][key]

    // ---- Q fragments (A layout), folded 1/sqrt(DK)=0.125 scale ----
    f16x8 qa[2];
    {
        const float* qp = Qp + (size_t)(q0 + wv * 16 + n16) * D_K + qd * 8;
#pragma unroll
        for (int kc = 0; kc < 2; ++kc) {
            float4 x0 = *(const float4*)(qp + kc * 32);
            float4 x1 = *(const float4*)(qp + kc * 32 + 4);
            f16x8 a;
            a[0]=(f16)(x0.x*0.125f); a[1]=(f16)(x0.y*0.125f);
            a[2]=(f16)(x0.z*0.125f); a[3]=(f16)(x0.w*0.125f);
            a[4]=(f16)(x1.x*0.125f); a[5]=(f16)(x1.y*0.125f);
            a[6]=(f16)(x1.z*0.125f); a[7]=(f16)(x1.w*0.125f);
            qa[kc] = a;
        }
    }

    float m_i[4], l_i[4];
    f32x4 oa[4];
#pragma unroll
    for (int r = 0; r < 4; ++r) { m_i[r] = -3.0e38f; l_i[r] = 0.f; }
#pragma unroll
    for (int nc = 0; nc < 4; ++nc) oa[nc] = (f32x4){0.f, 0.f, 0.f, 0.f};

    const int qrow0 = q0 + wv * 16 + qd * 4;   // C-layout row base for this lane

    for (int kb = 0; kb < S_DIM / BK; ++kb) {
        const int k0 = kb * BK;
        __syncthreads();   // previous iteration's LDS reads complete

        // ---- stage K block -> LDS fp16 (coalesced float4 reads) ----
#pragma unroll
        for (int i = 0; i < 4; ++i) {
            int fidx = tid + i * 256;              // 0..1023
            int key  = fidx >> 4;
            int dk4  = (fidx & 15) << 2;
            float4 kv = *(const float4*)(Kp + (size_t)(k0 + key) * D_K + dk4);
            f16x4 h; h[0]=(f16)kv.x; h[1]=(f16)kv.y; h[2]=(f16)kv.z; h[3]=(f16)kv.w;
            *(f16x4*)&Ksh[key][dk4] = h;
        }
        // ---- stage V block transposed (pair-packed half2 writes) ----
#pragma unroll
        for (int i = 0; i < 2; ++i) {
            int fidx = tid + i * 256;              // 0..511
            int kp2  = fidx >> 4;                  // key pair 0..31
            int dk4  = (fidx & 15) << 2;
            const float* vp = Vp + (size_t)(k0 + kp2 * 2) * D_K + dk4;
            float4 v0 = *(const float4*)(vp);
            float4 v1 = *(const float4*)(vp + D_K);
            float v0a[4] = {v0.x, v0.y, v0.z, v0.w};
            float v1a[4] = {v1.x, v1.y, v1.z, v1.w};
#pragma unroll
            for (int c = 0; c < 4; ++c) {
                f16x2 h; h[0] = (f16)v0a[c]; h[1] = (f16)v1a[c];
                *(f16x2*)&Vsh[dk4 + c][kp2 * 2] = h;
            }
        }
        __syncthreads();

        // ---- matrix + mask loads (streaming, C-layout positions) ----
        float mt[4][4];
        int mbits = 0;
        {
            const size_t base = (size_t)qrow0 * S_DIM + k0 + n16;
#pragma unroll
            for (int r = 0; r < 4; ++r)
#pragma unroll
                for (int cc = 0; cc < 4; ++cc)
                    mt[r][cc] = __builtin_nontemporal_load(Mp + base + (size_t)r * S_DIM + cc * 16);
            if (mfmt == 1) {
#pragma unroll
                for (int r = 0; r < 4; ++r)
#pragma unroll
                    for (int cc = 0; cc < 4; ++cc)
                        if (__builtin_nontemporal_load(mB + base + (size_t)r * S_DIM + cc * 16))
                            mbits |= 1 << (r * 4 + cc);
            } else if (mfmt == 0) {
#pragma unroll
                for (int r = 0; r < 4; ++r)
#pragma unroll
                    for (int cc = 0; cc < 4; ++cc)
                        if (__builtin_nontemporal_load(mI + base + (size_t)r * S_DIM + cc * 16))
                            mbits |= 1 << (r * 4 + cc);
            } else {
#pragma unroll
                for (int r = 0; r < 4; ++r)
#pragma unroll
                    for (int cc = 0; cc < 4; ++cc)
                        if (__builtin_nontemporal_load(mF + base + (size_t)r * S_DIM + cc * 16) != 0.f)
                            mbits |= 1 << (r * 4 + cc);
            }
        }

        // ---- S = (Q/8) K^T via MFMA ----
        f32x4 sc[4];
#pragma unroll
        for (int cc = 0; cc < 4; ++cc) {
            f32x4 acc = (f32x4){0.f, 0.f, 0.f, 0.f};
#pragma unroll
            for (int kc = 0; kc < 2; ++kc) {
                f16x8 b = *(const f16x8*)&Ksh[cc * 16 + n16][kc * 32 + qd * 8];
                acc = __builtin_amdgcn_mfma_f32_16x16x32_f16(qa[kc], b, acc, 0, 0, 0);
            }
            sc[cc] = acc;
        }

        // ---- scale by matrix, apply mask ----
#pragma unroll
        for (int cc = 0; cc < 4; ++cc)
#pragma unroll
            for (int r = 0; r < 4; ++r) {
                float s = sc[cc][r] * mt[r][cc];
                sc[cc][r] = ((mbits >> (r * 4 + cc)) & 1) ? NEGV : s;
            }

        // ---- online softmax (rows live across the 16 lanes of a quad) ----
        float alpha[4];
#pragma unroll
        for (int r = 0; r < 4; ++r) {
            float rm = fmaxf(fmaxf(sc[0][r], sc[1][r]), fmaxf(sc[2][r], sc[3][r]));
#pragma unroll
            for (int off = 1; off < 16; off <<= 1)
                rm = fmaxf(rm, __shfl_xor(rm, off, 64));
            float mn = fmaxf(m_i[r], rm);
            alpha[r] = __expf(m_i[r] - mn);
            m_i[r] = mn;
        }
        float rs[4] = {0.f, 0.f, 0.f, 0.f};
#pragma unroll
        for (int cc = 0; cc < 4; ++cc)
#pragma unroll
            for (int r = 0; r < 4; ++r) {
                float p = __expf(sc[cc][r] - m_i[r]);
                sc[cc][r] = p;
                rs[r] += p;
            }
#pragma unroll
        for (int r = 0; r < 4; ++r) {
#pragma unroll
            for (int off = 1; off < 16; off <<= 1)
                rs[r] += __shfl_xor(rs[r], off, 64);
            l_i[r] = l_i[r] * alpha[r] + rs[r];
        }

        // ---- P (C-layout) -> LDS -> A-layout; rescale O; O += P V ----
#pragma unroll
        for (int cc = 0; cc < 4; ++cc)
#pragma unroll
            for (int r = 0; r < 4; ++r)
                Psh[wv][qd * 4 + r][cc * 16 + n16] = (f16)sc[cc][r];

#pragma unroll
        for (int nc = 0; nc < 4; ++nc)
#pragma unroll
            for (int r = 0; r < 4; ++r)
                oa[nc][r] *= alpha[r];

#pragma unroll
        for (int kc = 0; kc < 2; ++kc) {
            f16x8 a = *(const f16x8*)&Psh[wv][n16][kc * 32 + qd * 8];
#pragma unroll
            for (int nc = 0; nc < 4; ++nc) {
                f16x8 b = *(const f16x8*)&Vsh[nc * 16 + n16][kc * 32 + qd * 8];
                oa[nc] = __builtin_amdgcn_mfma_f32_16x16x32_f16(a, b, oa[nc], 0, 0, 0);
            }
        }
    }

    // ---- epilogue: normalize and store ----
#pragma unroll
    for (int r = 0; r < 4; ++r) {
        float inv = 1.f / l_i[r];
#pragma unroll
        for (int nc = 0; nc < 4; ++nc) {
            size_t off = ((size_t)bh * S_DIM + (qrow0 + r)) * D_K + nc * 16 + n16;
            __builtin_nontemporal_store(oa[nc][r] * inv, Og + off);
        }
    }
}

extern "C" void kernel_launch(void* const* d_in, const int* in_sizes, int n_in,
                              void* d_out, int out_size, void* d_ws, size_t ws_size,
                              hipStream_t stream) {
    const float* Q      = (const float*)d_in[0];
    const float* K      = (const float*)d_in[1];
    const float* V      = (const float*)d_in[2];
    const void*  mask   = d_in[3];
    const float* matrix = (const float*)d_in[4];
    float* out = (float*)d_out;
    int* flag = (int*)d_ws;

    hipMemsetAsync(flag, 0, sizeof(int), stream);
    mask_probe<<<1, 256, 0, stream>>>((const unsigned int*)mask, flag);

    dim3 grid(S_DIM / BQ, 2 * 16);   // 32 q-blocks x 32 (b,h)
    attn_kernel<<<grid, 256, 0, stream>>>(Q, K, V, mask, matrix, out, flag);
}